// Round 5
// baseline (49.353 us; speedup 1.0000x reference)
//
#include <hip/hip_runtime.h>
#include <math.h>

#define TPB 256
#define B_TOTAL 524288
#define L2E 1.44269504088896340736f

#define RCP(x) __builtin_amdgcn_rcpf(x)

typedef float v2f __attribute__((ext_vector_type(2)));

__device__ __forceinline__ v2f bc(float s) { return (v2f){s, s}; }
__device__ __forceinline__ v2f pkfma(v2f a, v2f b, v2f c) {
    return __builtin_elementwise_fma(a, b, c);
}

// packed exp2 for t in [-12.5, 0.5]: rndne range-reduce + deg-4 Taylor + ldexp.
// all full-rate VALU ops (no quarter-rate v_exp_f32).
__device__ __forceinline__ v2f pexp2(v2f t) {
    v2f n = { __builtin_rintf(t.x), __builtin_rintf(t.y) };   // v_rndne_f32
    v2f f = t - n;                                            // f in [-0.5, 0.5]
    v2f r = pkfma(f, bc(0.00961813f), bc(0.05550411f));
    r = pkfma(f, r, bc(0.24022651f));
    r = pkfma(f, r, bc(0.69314718f));
    r = pkfma(f, r, bc(1.0f));
    return (v2f){ __builtin_ldexpf(r.x, (int)n.x),            // v_ldexp_f32
                  __builtin_ldexpf(r.y, (int)n.y) };
}

__global__ __launch_bounds__(TPB) void logic_net_kernel(
    const float* __restrict__ state,        // [B,18]
    const float* __restrict__ c_templates,  // [12,2]
    const float* __restrict__ c_gammas,     // [12,2]
    const float* __restrict__ a_templates,  // [6,2,2]
    const float* __restrict__ a_gammas,     // [6,2,2]
    const float* __restrict__ a_body_W,     // [6,2,4,2]
    const float* __restrict__ a_body_b,     // [6,2,4]
    const float* __restrict__ a_head_W,     // [6,2,4]
    const float* __restrict__ a_head_b,     // [6,2]
    const float* __restrict__ act_W,        // [9,12]
    const float* __restrict__ act_b,        // [9]
    float* __restrict__ out)                // [B,9]
{
    // Folded constants in exp2-space; packed over rule/clause PAIRS.
    // e = exp(-ms) = exp2(A + x0*(w0*x0 + c0) + x1*(w1*x1 + c1))
    __shared__ alignas(16) float sCc[60];   // [rp][k][half]: rp*10 + k*2 + half; k={A,w0,w1,c0,c1}
    __shared__ alignas(16) float sAa[60];
    __shared__ alignas(16) float sM[48];    // M[rj][p][l] = sum_v headW[r,l,v]*bodyW[rj,v,p]
    __shared__ alignas(16) float sAW[120];  // [(rl*5+ap)*2+half], action a=2ap+half (a=9 -> 0)
    __shared__ alignas(16) float sQ0[10];   // folded bias per action (padded)

    const int tid = threadIdx.x;

    // ---- issue my row's loads FIRST (latency hides under fold + barrier) ----
    const int row = blockIdx.x * TPB + tid;
    const float* st = state + (size_t)row * 18;
    v2f p[9];
    #pragma unroll
    for (int i = 0; i < 9; ++i) p[i] = *(const v2f*)(st + 2*i);   // {b0_i, b1_i}

    // ---- fold constants, once per block, disjoint thread ranges ----
    if (tid < 12) {
        int r = tid;
        float t0 = c_templates[2*r], t1 = c_templates[2*r+1];
        float g0 = fminf(fmaxf(c_gammas[2*r],   0.f), 1.f);
        float g1 = fminf(fmaxf(c_gammas[2*r+1], 0.f), 1.f);
        float W0 = (1.f - g0) * L2E, W1 = (1.f - g1) * L2E;
        int b = (r >> 1) * 10, h = r & 1;
        sCc[b + 0 + h] = -(W0*t0*t0 + W1*t1*t1);
        sCc[b + 2 + h] = -W0;
        sCc[b + 4 + h] = -W1;
        sCc[b + 6 + h] = 2.f*W0*t0;
        sCc[b + 8 + h] = 2.f*W1*t1;
    } else if (tid < 24) {
        int rj = tid - 12;
        float t0 = a_templates[2*rj], t1 = a_templates[2*rj+1];
        float g0 = fminf(fmaxf(a_gammas[2*rj],   0.f), 1.f);
        float g1 = fminf(fmaxf(a_gammas[2*rj+1], 0.f), 1.f);
        float W0 = (1.f - g0) * L2E, W1 = (1.f - g1) * L2E;
        int b = (rj >> 1) * 10, h = rj & 1;
        sAa[b + 0 + h] = -(W0*t0*t0 + W1*t1*t1);
        sAa[b + 2 + h] = -W0;
        sAa[b + 4 + h] = -W1;
        sAa[b + 6 + h] = 2.f*W0*t0;
        sAa[b + 8 + h] = 2.f*W1*t1;
    } else if (tid < 72) {
        int m = tid - 24;              // 0..47
        int rj = m >> 2, pp = (m >> 1) & 1, l = m & 1, r = rj >> 1;
        float s = 0.f;
        #pragma unroll
        for (int v = 0; v < 4; ++v)
            s += a_head_W[(r*2 + l)*4 + v] * a_body_W[(rj*4 + v)*2 + pp];
        sM[m] = s;
    } else if (tid < 192) {
        int m = tid - 72;              // 0..119
        int rl = m / 10, a = m % 10;
        sAW[m] = (a < 9) ? act_W[a*12 + rl] : 0.f;
    } else if (tid < 201) {
        int a = tid - 192;
        float s = act_b[a];
        #pragma unroll
        for (int r = 0; r < 6; ++r) {
            #pragma unroll
            for (int l = 0; l < 2; ++l) {
                float h = a_head_b[r*2 + l];
                #pragma unroll
                for (int v = 0; v < 4; ++v)
                    h += a_head_W[(r*2+l)*4 + v] *
                         (a_body_b[(r*2)*4 + v] + a_body_b[(r*2+1)*4 + v]);
                s += act_W[a*12 + 2*r + l] * h;
            }
        }
        sQ0[a] = s;
    } else if (tid == 201) {
        sQ0[9] = 0.f;
    }

    __syncthreads();

    // ---- ConcreteLayer: packed over rule pairs, factored Horner form ----
    v2f cf0p[6], cf1p[6];
    #pragma unroll
    for (int rp = 0; rp < 6; ++rp) {
        const v2f A2  = *(const v2f*)&sCc[rp*10 + 0];
        const v2f W02 = *(const v2f*)&sCc[rp*10 + 2];
        const v2f W12 = *(const v2f*)&sCc[rp*10 + 4];
        const v2f C02 = *(const v2f*)&sCc[rp*10 + 6];
        const v2f C12 = *(const v2f*)&sCc[rp*10 + 8];
        v2f mx2 = (v2f){0.f, 0.f}, se2 = (v2f){0.f, 0.f}, s12 = (v2f){0.f, 0.f};
        #pragma unroll
        for (int i = 0; i < 9; ++i) {
            const float b0 = p[i].x, b1 = p[i].y;
            v2f h0 = pkfma(W02, bc(b0), C02);
            v2f h1 = pkfma(W12, bc(b1), C12);
            v2f t2 = pkfma(h0, bc(b0), A2);
            t2 = pkfma(h1, bc(b1), t2);
            v2f e2 = pexp2(t2);
            mx2 = __builtin_elementwise_max(mx2, e2);
            se2 += e2;
            s12 = pkfma(e2, bc(b1), s12);
        }
        cf0p[rp] = mx2;                        // pattern_strength = max e
        cf1p[rp] = s12 * (v2f){RCP(se2.x), RCP(se2.y)};
    }

    // ---- AbstractionLayer: packed over clause pairs, factored form ----
    v2f y2[6];
    #pragma unroll
    for (int cp = 0; cp < 6; ++cp) {
        const v2f A2  = *(const v2f*)&sAa[cp*10 + 0];
        const v2f W02 = *(const v2f*)&sAa[cp*10 + 2];
        const v2f W12 = *(const v2f*)&sAa[cp*10 + 4];
        const v2f C02 = *(const v2f*)&sAa[cp*10 + 6];
        const v2f C12 = *(const v2f*)&sAa[cp*10 + 8];
        v2f se2 = (v2f){0.f, 0.f}, q02 = (v2f){0.f, 0.f}, q12 = (v2f){0.f, 0.f};
        #pragma unroll
        for (int i = 0; i < 12; ++i) {
            const float c0 = cf0p[i >> 1][i & 1];
            const float c1 = cf1p[i >> 1][i & 1];
            v2f h0 = pkfma(W02, bc(c0), C02);
            v2f h1 = pkfma(W12, bc(c1), C12);
            v2f t2 = pkfma(h0, bc(c0), A2);
            t2 = pkfma(h1, bc(c1), t2);
            v2f e2 = pexp2(t2);
            se2 += e2;
            q02 = pkfma(e2, bc(c0), q02);
            q12 = pkfma(e2, bc(c1), q12);
        }
        v2f inv2  = (v2f){RCP(se2.x), RCP(se2.y)};
        v2f sel02 = q02 * inv2;
        v2f sel12 = q12 * inv2;
        v2f y = bc(sel02.x) * (*(const v2f*)&sM[(2*cp)*4 + 0]);
        y = pkfma(bc(sel12.x), *(const v2f*)&sM[(2*cp)*4 + 2], y);
        y = pkfma(bc(sel02.y), *(const v2f*)&sM[(2*cp+1)*4 + 0], y);
        y = pkfma(bc(sel12.y), *(const v2f*)&sM[(2*cp+1)*4 + 2], y);
        y2[cp] = y;
    }

    // ---- ActionLayer: packed over action pairs ----
    v2f Q[5];
    #pragma unroll
    for (int ap = 0; ap < 5; ++ap) Q[ap] = *(const v2f*)&sQ0[ap*2];
    #pragma unroll
    for (int rl = 0; rl < 12; ++rl) {
        const v2f yv = bc(y2[rl >> 1][rl & 1]);
        #pragma unroll
        for (int ap = 0; ap < 5; ++ap)
            Q[ap] = pkfma(yv, *(const v2f*)&sAW[(rl*5 + ap)*2], Q[ap]);
    }

    // ---- store 9 floats ----
    float* op = out + (size_t)row * 9;
    #pragma unroll
    for (int a = 0; a < 9; ++a) op[a] = Q[a >> 1][a & 1];
}

extern "C" void kernel_launch(void* const* d_in, const int* in_sizes, int n_in,
                              void* d_out, int out_size, void* d_ws, size_t ws_size,
                              hipStream_t stream) {
    const float* state       = (const float*)d_in[0];
    const float* c_templates = (const float*)d_in[1];
    const float* c_gammas    = (const float*)d_in[2];
    const float* a_templates = (const float*)d_in[3];
    const float* a_gammas    = (const float*)d_in[4];
    const float* a_body_W    = (const float*)d_in[5];
    const float* a_body_b    = (const float*)d_in[6];
    const float* a_head_W    = (const float*)d_in[7];
    const float* a_head_b    = (const float*)d_in[8];
    const float* act_W       = (const float*)d_in[9];
    const float* act_b       = (const float*)d_in[10];
    float* out = (float*)d_out;

    const int blocks = B_TOTAL / TPB;  // 2048
    logic_net_kernel<<<blocks, TPB, 0, stream>>>(
        state, c_templates, c_gammas, a_templates, a_gammas,
        a_body_W, a_body_b, a_head_W, a_head_b, act_W, act_b, out);
}

// Round 6
// 35.827 us; speedup vs baseline: 1.3775x; 1.3775x over previous
//
#include <hip/hip_runtime.h>
#include <math.h>

#define TPB 256
#define ROWS 2
#define B_TOTAL 524288
#define L2E 1.44269504088896340736f

#if __has_builtin(__builtin_amdgcn_exp2f)
#define EXP2(x) __builtin_amdgcn_exp2f(x)
#else
#define EXP2(x) exp2f(x)
#endif
#define RCP(x) __builtin_amdgcn_rcpf(x)

typedef float v2f __attribute__((ext_vector_type(2)));

__device__ __forceinline__ v2f bc(float s) { return (v2f){s, s}; }
__device__ __forceinline__ v2f pkfma(v2f a, v2f b, v2f c) {
    return __builtin_elementwise_fma(a, b, c);
}

__global__ __launch_bounds__(TPB) void logic_net_kernel(
    const float* __restrict__ state,        // [B,18]
    const float* __restrict__ c_templates,  // [12,2]
    const float* __restrict__ c_gammas,     // [12,2]
    const float* __restrict__ a_templates,  // [6,2,2]
    const float* __restrict__ a_gammas,     // [6,2,2]
    const float* __restrict__ a_body_W,     // [6,2,4,2]
    const float* __restrict__ a_body_b,     // [6,2,4]
    const float* __restrict__ a_head_W,     // [6,2,4]
    const float* __restrict__ a_head_b,     // [6,2]
    const float* __restrict__ act_W,        // [9,12]
    const float* __restrict__ act_b,        // [9]
    float* __restrict__ out)                // [B,9]
{
    // Folded constants in exp2-space; packed over rule/clause PAIRS.
    // e = exp(-ms) = exp2(A + x0*(w0*x0 + c0) + x1*(w1*x1 + c1))
    __shared__ alignas(16) float sCc[60];   // [rp][k][half]: rp*10 + k*2 + half; k={A,w0,w1,c0,c1}
    __shared__ alignas(16) float sAa[60];
    __shared__ alignas(16) float sM[48];    // M[rj][p][l] = sum_v headW[r,l,v]*bodyW[rj,v,p]
    __shared__ alignas(16) float sAW[120];  // [(rl*5+ap)*2+half], action a=2ap+half (a=9 -> 0)
    __shared__ alignas(16) float sQ0[10];   // folded bias per action (padded)

    const int tid = threadIdx.x;

    // ---- issue both rows' loads FIRST (latency hides under fold + barrier) ----
    const int row0 = blockIdx.x * (TPB * ROWS) + tid;   // this thread: rows row0, row0+TPB
    const float* st = state + (size_t)row0 * 18;
    v2f p[ROWS][9];
    #pragma unroll
    for (int q = 0; q < ROWS; ++q)
        #pragma unroll
        for (int i = 0; i < 9; ++i)
            p[q][i] = *(const v2f*)(st + q * (TPB * 18) + 2 * i);

    // ---- fold constants, once per block, disjoint thread ranges ----
    if (tid < 12) {
        int r = tid;
        float t0 = c_templates[2*r], t1 = c_templates[2*r+1];
        float g0 = fminf(fmaxf(c_gammas[2*r],   0.f), 1.f);
        float g1 = fminf(fmaxf(c_gammas[2*r+1], 0.f), 1.f);
        float W0 = (1.f - g0) * L2E, W1 = (1.f - g1) * L2E;
        int b = (r >> 1) * 10, h = r & 1;
        sCc[b + 0 + h] = -(W0*t0*t0 + W1*t1*t1);
        sCc[b + 2 + h] = -W0;
        sCc[b + 4 + h] = -W1;
        sCc[b + 6 + h] = 2.f*W0*t0;
        sCc[b + 8 + h] = 2.f*W1*t1;
    } else if (tid < 24) {
        int rj = tid - 12;
        float t0 = a_templates[2*rj], t1 = a_templates[2*rj+1];
        float g0 = fminf(fmaxf(a_gammas[2*rj],   0.f), 1.f);
        float g1 = fminf(fmaxf(a_gammas[2*rj+1], 0.f), 1.f);
        float W0 = (1.f - g0) * L2E, W1 = (1.f - g1) * L2E;
        int b = (rj >> 1) * 10, h = rj & 1;
        sAa[b + 0 + h] = -(W0*t0*t0 + W1*t1*t1);
        sAa[b + 2 + h] = -W0;
        sAa[b + 4 + h] = -W1;
        sAa[b + 6 + h] = 2.f*W0*t0;
        sAa[b + 8 + h] = 2.f*W1*t1;
    } else if (tid < 72) {
        int m = tid - 24;              // 0..47
        int rj = m >> 2, pp = (m >> 1) & 1, l = m & 1, r = rj >> 1;
        float s = 0.f;
        #pragma unroll
        for (int v = 0; v < 4; ++v)
            s += a_head_W[(r*2 + l)*4 + v] * a_body_W[(rj*4 + v)*2 + pp];
        sM[m] = s;
    } else if (tid < 192) {
        int m = tid - 72;              // 0..119
        int rl = m / 10, a = m % 10;
        sAW[m] = (a < 9) ? act_W[a*12 + rl] : 0.f;
    } else if (tid < 201) {
        int a = tid - 192;
        float s = act_b[a];
        #pragma unroll
        for (int r = 0; r < 6; ++r) {
            #pragma unroll
            for (int l = 0; l < 2; ++l) {
                float h = a_head_b[r*2 + l];
                #pragma unroll
                for (int v = 0; v < 4; ++v)
                    h += a_head_W[(r*2+l)*4 + v] *
                         (a_body_b[(r*2)*4 + v] + a_body_b[(r*2+1)*4 + v]);
                s += act_W[a*12 + 2*r + l] * h;
            }
        }
        sQ0[a] = s;
    } else if (tid == 201) {
        sQ0[9] = 0.f;
    }

    __syncthreads();

    // ---- ConcreteLayer: packed over rule pairs, 2 rows interleaved ----
    v2f cf0p[ROWS][6], cf1p[ROWS][6];
    #pragma unroll
    for (int rp = 0; rp < 6; ++rp) {
        const v2f A2  = *(const v2f*)&sCc[rp*10 + 0];
        const v2f W02 = *(const v2f*)&sCc[rp*10 + 2];
        const v2f W12 = *(const v2f*)&sCc[rp*10 + 4];
        const v2f C02 = *(const v2f*)&sCc[rp*10 + 6];
        const v2f C12 = *(const v2f*)&sCc[rp*10 + 8];
        v2f mx2[ROWS], se2[ROWS], s12[ROWS];
        #pragma unroll
        for (int q = 0; q < ROWS; ++q) {
            mx2[q] = (v2f){0.f, 0.f}; se2[q] = (v2f){0.f, 0.f}; s12[q] = (v2f){0.f, 0.f};
        }
        #pragma unroll
        for (int i = 0; i < 9; ++i) {
            #pragma unroll
            for (int q = 0; q < ROWS; ++q) {
                const float b0 = p[q][i].x, b1 = p[q][i].y;
                v2f h0 = pkfma(W02, bc(b0), C02);
                v2f h1 = pkfma(W12, bc(b1), C12);
                v2f t2 = pkfma(h0, bc(b0), A2);
                t2 = pkfma(h1, bc(b1), t2);
                v2f e2 = (v2f){EXP2(t2.x), EXP2(t2.y)};
                mx2[q] = __builtin_elementwise_max(mx2[q], e2);
                se2[q] += e2;
                s12[q] = pkfma(e2, bc(b1), s12[q]);
            }
        }
        #pragma unroll
        for (int q = 0; q < ROWS; ++q) {
            cf0p[q][rp] = mx2[q];          // pattern_strength = max e
            cf1p[q][rp] = s12[q] * (v2f){RCP(se2[q].x), RCP(se2[q].y)};
        }
    }

    // ---- AbstractionLayer: packed over clause pairs, 2 rows interleaved ----
    v2f y2[ROWS][6];
    #pragma unroll
    for (int cp = 0; cp < 6; ++cp) {
        const v2f A2  = *(const v2f*)&sAa[cp*10 + 0];
        const v2f W02 = *(const v2f*)&sAa[cp*10 + 2];
        const v2f W12 = *(const v2f*)&sAa[cp*10 + 4];
        const v2f C02 = *(const v2f*)&sAa[cp*10 + 6];
        const v2f C12 = *(const v2f*)&sAa[cp*10 + 8];
        v2f se2[ROWS], q02[ROWS], q12[ROWS];
        #pragma unroll
        for (int q = 0; q < ROWS; ++q) {
            se2[q] = (v2f){0.f, 0.f}; q02[q] = (v2f){0.f, 0.f}; q12[q] = (v2f){0.f, 0.f};
        }
        #pragma unroll
        for (int i = 0; i < 12; ++i) {
            #pragma unroll
            for (int q = 0; q < ROWS; ++q) {
                const float c0 = cf0p[q][i >> 1][i & 1];
                const float c1 = cf1p[q][i >> 1][i & 1];
                v2f h0 = pkfma(W02, bc(c0), C02);
                v2f h1 = pkfma(W12, bc(c1), C12);
                v2f t2 = pkfma(h0, bc(c0), A2);
                t2 = pkfma(h1, bc(c1), t2);
                v2f e2 = (v2f){EXP2(t2.x), EXP2(t2.y)};
                se2[q] += e2;
                q02[q] = pkfma(e2, bc(c0), q02[q]);
                q12[q] = pkfma(e2, bc(c1), q12[q]);
            }
        }
        #pragma unroll
        for (int q = 0; q < ROWS; ++q) {
            v2f inv2  = (v2f){RCP(se2[q].x), RCP(se2[q].y)};
            v2f sel02 = q02[q] * inv2;
            v2f sel12 = q12[q] * inv2;
            v2f y = bc(sel02.x) * (*(const v2f*)&sM[(2*cp)*4 + 0]);
            y = pkfma(bc(sel12.x), *(const v2f*)&sM[(2*cp)*4 + 2], y);
            y = pkfma(bc(sel02.y), *(const v2f*)&sM[(2*cp+1)*4 + 0], y);
            y = pkfma(bc(sel12.y), *(const v2f*)&sM[(2*cp+1)*4 + 2], y);
            y2[q][cp] = y;
        }
    }

    // ---- ActionLayer + store, per row ----
    #pragma unroll
    for (int q = 0; q < ROWS; ++q) {
        v2f Q[5];
        #pragma unroll
        for (int ap = 0; ap < 5; ++ap) Q[ap] = *(const v2f*)&sQ0[ap*2];
        #pragma unroll
        for (int rl = 0; rl < 12; ++rl) {
            const v2f yv = bc(y2[q][rl >> 1][rl & 1]);
            #pragma unroll
            for (int ap = 0; ap < 5; ++ap)
                Q[ap] = pkfma(yv, *(const v2f*)&sAW[(rl*5 + ap)*2], Q[ap]);
        }
        float* op = out + (size_t)(row0 + q * TPB) * 9;
        #pragma unroll
        for (int a = 0; a < 9; ++a) op[a] = Q[a >> 1][a & 1];
    }
}

extern "C" void kernel_launch(void* const* d_in, const int* in_sizes, int n_in,
                              void* d_out, int out_size, void* d_ws, size_t ws_size,
                              hipStream_t stream) {
    const float* state       = (const float*)d_in[0];
    const float* c_templates = (const float*)d_in[1];
    const float* c_gammas    = (const float*)d_in[2];
    const float* a_templates = (const float*)d_in[3];
    const float* a_gammas    = (const float*)d_in[4];
    const float* a_body_W    = (const float*)d_in[5];
    const float* a_body_b    = (const float*)d_in[6];
    const float* a_head_W    = (const float*)d_in[7];
    const float* a_head_b    = (const float*)d_in[8];
    const float* act_W       = (const float*)d_in[9];
    const float* act_b       = (const float*)d_in[10];
    float* out = (float*)d_out;

    const int blocks = B_TOTAL / (TPB * ROWS);  // 1024
    logic_net_kernel<<<blocks, TPB, 0, stream>>>(
        state, c_templates, c_gammas, a_templates, a_gammas,
        a_body_W, a_body_b, a_head_W, a_head_b, act_W, act_b, out);
}